// Round 8
// baseline (1014.659 us; speedup 1.0000x reference)
//
#include <hip/hip_runtime.h>
#include <hip/hip_bf16.h>

#define EPS  1e-5f
#define SPAN 400          // dst nodes per bin (compile-time divisor)
#define MAXB 256          // max bins (N <= 102400)
#define PBE  2048         // edges per k_pairs block
typedef __hip_bfloat16 bf16;
typedef int iv4 __attribute__((ext_vector_type(4)));
typedef int iv2 __attribute__((ext_vector_type(2)));

// ---------------------------------------------------------------------------
// Pass 1: 250-bin histogram of dst (bin = d/SPAN). Edge stream nt, read once.
// ---------------------------------------------------------------------------
__global__ void k_hist(const int* __restrict__ dst, int* __restrict__ binCnt, int nE)
{
    __shared__ int hist[MAXB];
    int t = threadIdx.x;
    for (int k = t; k < MAXB; k += blockDim.x) hist[k] = 0;
    __syncthreads();
    int tid = blockIdx.x * blockDim.x + t;
    int stride = gridDim.x * blockDim.x;
    const iv4* d4 = (const iv4*)dst;
    int n4 = nE >> 2;
    for (int e = tid; e < n4; e += stride) {
        iv4 d = __builtin_nontemporal_load(&d4[e]);
        atomicAdd(&hist[d.x / SPAN], 1);
        atomicAdd(&hist[d.y / SPAN], 1);
        atomicAdd(&hist[d.z / SPAN], 1);
        atomicAdd(&hist[d.w / SPAN], 1);
    }
    if (blockIdx.x == 0 && t == 0)
        for (int e = n4 << 2; e < nE; ++e) atomicAdd(&hist[dst[e] / SPAN], 1);
    __syncthreads();
    for (int k = t; k < MAXB; k += blockDim.x)
        if (hist[k]) atomicAdd(&binCnt[k], hist[k]);
}

// ---------------------------------------------------------------------------
// Exclusive scan of bin counts (one 256-thread block)
// ---------------------------------------------------------------------------
__global__ void k_binscan(const int* __restrict__ binCnt, int* __restrict__ binStart,
                          int* __restrict__ binCur, int nbins, int nE)
{
    __shared__ int ls[MAXB];
    int t = threadIdx.x;
    ls[t] = (t < nbins) ? binCnt[t] : 0;
    __syncthreads();
#pragma unroll
    for (int off = 1; off < MAXB; off <<= 1) {
        int u = (t >= off) ? ls[t - off] : 0;
        __syncthreads();
        ls[t] += u;
        __syncthreads();
    }
    int start = (t == 0) ? 0 : ls[t - 1];
    if (t < nbins) { binStart[t] = start; binCur[t] = start; }
    if (t == 0) binStart[nbins] = nE;
}

// ---------------------------------------------------------------------------
// Pass 2: partition (dst,src) pairs into bin-contiguous staging.
// Per 2048-edge block: LDS hist -> one global reservation per bin -> emit.
// Each block's per-bin region (~64B) is fully written by that block.
// ---------------------------------------------------------------------------
__global__ void k_pairs(const int* __restrict__ src, const int* __restrict__ dst,
                        int* __restrict__ binCur, iv2* __restrict__ stg, int nE)
{
    __shared__ int hist[MAXB], base[MAXB], cur[MAXB];
    int t = threadIdx.x;
    for (int k = t; k < MAXB; k += 256) { hist[k] = 0; cur[k] = 0; }
    __syncthreads();
    const iv4* d4 = (const iv4*)dst;
    const iv4* s4 = (const iv4*)src;
    int n4 = nE >> 2;
    int i0 = blockIdx.x * (PBE / 4) + 2 * t;
    bool v0 = i0 < n4, v1 = i0 + 1 < n4;
    iv4 d0 = {0,0,0,0}, s0 = {0,0,0,0}, d1 = {0,0,0,0}, s1 = {0,0,0,0};
    if (v0) { d0 = __builtin_nontemporal_load(&d4[i0]);     s0 = __builtin_nontemporal_load(&s4[i0]); }
    if (v1) { d1 = __builtin_nontemporal_load(&d4[i0 + 1]); s1 = __builtin_nontemporal_load(&s4[i0 + 1]); }
    if (v0) {
        atomicAdd(&hist[d0.x / SPAN], 1); atomicAdd(&hist[d0.y / SPAN], 1);
        atomicAdd(&hist[d0.z / SPAN], 1); atomicAdd(&hist[d0.w / SPAN], 1);
    }
    if (v1) {
        atomicAdd(&hist[d1.x / SPAN], 1); atomicAdd(&hist[d1.y / SPAN], 1);
        atomicAdd(&hist[d1.z / SPAN], 1); atomicAdd(&hist[d1.w / SPAN], 1);
    }
    bool tailblk = (blockIdx.x == gridDim.x - 1) && (t == 0);
    if (tailblk)
        for (int e = n4 << 2; e < nE; ++e) atomicAdd(&hist[dst[e] / SPAN], 1);
    __syncthreads();
    for (int k = t; k < MAXB; k += 256) {
        int tot = hist[k];
        base[k] = tot ? atomicAdd(&binCur[k], tot) : 0;
    }
    __syncthreads();
#define EMIT(dd, ss_) { int b = (dd) / SPAN; \
        int p = base[b] + atomicAdd(&cur[b], 1); \
        iv2 pr; pr.x = (dd); pr.y = (ss_); stg[p] = pr; }
    if (v0) { EMIT(d0.x, s0.x) EMIT(d0.y, s0.y) EMIT(d0.z, s0.z) EMIT(d0.w, s0.w) }
    if (v1) { EMIT(d1.x, s1.x) EMIT(d1.y, s1.y) EMIT(d1.z, s1.z) EMIT(d1.w, s1.w) }
    if (tailblk)
        for (int e = n4 << 2; e < nE; ++e) { EMIT(dst[e], src[e]) }
#undef EMIT
}

// ---------------------------------------------------------------------------
// Layer 1 per bin: LDS-aggregate x + degree count, then BN+ReLU transform.
// Writes inv_cnt (global, reused by later layers) and h1 (bf16).
// ---------------------------------------------------------------------------
__global__ __launch_bounds__(1024) void k_lyr1(
    const iv2* __restrict__ stg, const int* __restrict__ binStart,
    const float* __restrict__ x,
    const float* __restrict__ W1l, const float* __restrict__ b1l,
    const float* __restrict__ W1r,
    const float* __restrict__ gam, const float* __restrict__ bet,
    const float* __restrict__ mu,  const float* __restrict__ var,
    float* __restrict__ inv_cnt, bf16* __restrict__ hout, int n)
{
    __shared__ float sagg[SPAN];
    __shared__ int   scnt[SPAN];
    __shared__ float sWl[16], sb[16], sWr[16], ssc[16], sbi[16];
    int t = threadIdx.x;
    int bin = blockIdx.x, lo = bin * SPAN;
    int nn = min(SPAN, n - lo);
    for (int k = t; k < SPAN; k += 1024) { sagg[k] = 0.0f; scnt[k] = 0; }
    if (t < 16) {
        sWl[t] = W1l[t]; sb[t] = b1l[t]; sWr[t] = W1r[t];
        float sc = gam[t] * rsqrtf(var[t] + EPS);
        ssc[t] = sc; sbi[t] = bet[t] - mu[t] * sc;
    }
    __syncthreads();
    int e0 = binStart[bin], e1 = binStart[bin + 1];
#pragma unroll 4
    for (int e = e0 + t; e < e1; e += 1024) {
        iv2 p = __builtin_nontemporal_load(&stg[e]);
        atomicAdd(&sagg[p.x - lo], x[p.y]);
        atomicAdd(&scnt[p.x - lo], 1);
    }
    __syncthreads();
    for (int j = t; j < nn; j += 1024) {
        int i = lo + j;
        float ic = 1.0f / fmaxf((float)scnt[j], 1.0f);
        inv_cnt[i] = ic;
        float mean = sagg[j] * ic;
        float xv = x[i];
        bf16* row = hout + (size_t)i * 16;
#pragma unroll
        for (int f = 0; f < 16; ++f) {
            float v = fmaf(mean, sWl[f], sb[f]);
            v = fmaf(xv, sWr[f], v);
            row[f] = __float2bfloat16(fmaxf(fmaf(v, ssc[f], sbi[f]), 0.0f));
        }
    }
}

// ---------------------------------------------------------------------------
// Layers 2,3 per bin: LDS-aggregate 16 bf16 feats + 16->16 transform + ReLU.
// ---------------------------------------------------------------------------
__global__ __launch_bounds__(1024) void k_lyr16(
    const iv2* __restrict__ stg, const int* __restrict__ binStart,
    const float* __restrict__ inv_cnt, const bf16* __restrict__ hin,
    const float* __restrict__ Wl, const float* __restrict__ bl,
    const float* __restrict__ Wr,
    bf16* __restrict__ hout, int n)
{
    __shared__ float sagg[SPAN * 17];
    __shared__ float sown[SPAN * 17];
    __shared__ float sWlT[256], sWrT[256], sb[16];
    int t = threadIdx.x;
    int bin = blockIdx.x, lo = bin * SPAN;
    int nn = min(SPAN, n - lo);
    for (int k = t; k < SPAN * 17; k += 1024) sagg[k] = 0.0f;
    if (t < 256) { int j = t & 15, ii = t >> 4; sWlT[ii*16+j] = Wl[j*16+ii]; sWrT[ii*16+j] = Wr[j*16+ii]; }
    if (t < 16) sb[t] = bl[t];
    for (int k = t; k < nn * 16; k += 1024) {
        int j = k >> 4, f = k & 15;
        sown[j * 17 + f] = __bfloat162float(hin[(size_t)(lo + j) * 16 + f]);
    }
    __syncthreads();
    int e0 = binStart[bin], e1 = binStart[bin + 1];
    int grp = t >> 4, f = t & 15;
#pragma unroll 4
    for (int e = e0 + grp; e < e1; e += 64) {
        iv2 p = __builtin_nontemporal_load(&stg[e]);        // broadcast to 16 lanes
        float v = __bfloat162float(hin[(size_t)p.y * 16 + f]);  // 32B/edge sector
        atomicAdd(&sagg[(p.x - lo) * 17 + f], v);           // ds_add_f32
    }
    __syncthreads();
    for (int k = t; k < nn * 16; k += 1024) {
        int j = k >> 4, ff = k & 15;
        float ic = inv_cnt[lo + j];
        float o = sb[ff];
#pragma unroll
        for (int ii = 0; ii < 16; ++ii) {
            o = fmaf(sagg[j * 17 + ii] * ic, sWlT[ii * 16 + ff], o);
            o = fmaf(sown[j * 17 + ii],      sWrT[ii * 16 + ff], o);
        }
        hout[(size_t)(lo + j) * 16 + ff] = __float2bfloat16(fmaxf(o, 0.0f));
    }
}

// ---------------------------------------------------------------------------
// Layer 4 + decoder + softmax per bin (LDS aggregate, then 64-node tiles).
// ---------------------------------------------------------------------------
__global__ __launch_bounds__(1024) void k_lyrfin(
    const iv2* __restrict__ stg, const int* __restrict__ binStart,
    const float* __restrict__ inv_cnt, const bf16* __restrict__ hin,
    const float* __restrict__ W4l, const float* __restrict__ b4l,
    const float* __restrict__ W4r,
    const float* __restrict__ Wd1, const float* __restrict__ bd1,
    const float* __restrict__ Wd2, const float* __restrict__ bd2,
    float* __restrict__ out, int n)
{
    __shared__ float sagg[SPAN * 17];
    __shared__ float sown[SPAN * 17];
    __shared__ float sW4lT[512], sW4rT[512], sb4[32];
    __shared__ float sWd1T[1024], sbd1[32], sWd2[64], sbd2[2];
    __shared__ float sH4[64][33];
    int t = threadIdx.x;
    int bin = blockIdx.x, lo = bin * SPAN;
    int nn = min(SPAN, n - lo);
    for (int k = t; k < SPAN * 17; k += 1024) sagg[k] = 0.0f;
    if (t < 512) { int j = t >> 4, ii = t & 15; sW4lT[ii*32+j] = W4l[t]; sW4rT[ii*32+j] = W4r[t]; }
    { int j = t >> 5, ii = t & 31; sWd1T[ii * 32 + j] = Wd1[t]; }   // t covers 0..1023
    if (t < 32) { sb4[t] = b4l[t]; sbd1[t] = bd1[t]; }
    if (t < 64) sWd2[t] = Wd2[t];
    if (t < 2)  sbd2[t] = bd2[t];
    for (int k = t; k < nn * 16; k += 1024) {
        int j = k >> 4, f = k & 15;
        sown[j * 17 + f] = __bfloat162float(hin[(size_t)(lo + j) * 16 + f]);
    }
    __syncthreads();
    int e0 = binStart[bin], e1 = binStart[bin + 1];
    int grp = t >> 4, f = t & 15;
#pragma unroll 4
    for (int e = e0 + grp; e < e1; e += 64) {
        iv2 p = __builtin_nontemporal_load(&stg[e]);
        float v = __bfloat162float(hin[(size_t)p.y * 16 + f]);
        atomicAdd(&sagg[(p.x - lo) * 17 + f], v);
    }
    __syncthreads();
    for (int bj = 0; bj < nn; bj += 64) {
        __syncthreads();
        int j = bj + grp;
        bool valid = j < nn;
        float o0 = 0.0f, o1 = 0.0f;
        if (valid) {
            float ic = inv_cnt[lo + j];
            float h4a = sb4[f], h4b = sb4[f + 16];
#pragma unroll
            for (int ii = 0; ii < 16; ++ii) {
                float a  = sagg[j * 17 + ii] * ic;
                float xx = sown[j * 17 + ii];
                h4a = fmaf(a,  sW4lT[ii * 32 + f],      h4a);
                h4b = fmaf(a,  sW4lT[ii * 32 + f + 16], h4b);
                h4a = fmaf(xx, sW4rT[ii * 32 + f],      h4a);
                h4b = fmaf(xx, sW4rT[ii * 32 + f + 16], h4b);
            }
            sH4[grp][f] = h4a;
            sH4[grp][f + 16] = h4b;
            // same-wave LDS write->read (16-lane group): lgkmcnt ordering suffices
            float za = sbd1[f], zb = sbd1[f + 16];
#pragma unroll
            for (int k2 = 0; k2 < 32; ++k2) {
                float hv = sH4[grp][k2];
                za = fmaf(hv, sWd1T[k2 * 32 + f],      za);
                zb = fmaf(hv, sWd1T[k2 * 32 + f + 16], zb);
            }
            za = fmaxf(za, 0.0f); zb = fmaxf(zb, 0.0f);
            o0 = za * sWd2[f]      + zb * sWd2[f + 16];
            o1 = za * sWd2[32 + f] + zb * sWd2[32 + f + 16];
        }
#pragma unroll
        for (int m = 8; m >= 1; m >>= 1) {
            o0 += __shfl_xor(o0, m, 64);
            o1 += __shfl_xor(o1, m, 64);
        }
        if (valid && f == 0) {
            o0 += sbd2[0]; o1 += sbd2[1];
            float mx = fmaxf(o0, o1);
            float ea = expf(o0 - mx), eb = expf(o1 - mx);
            float inv = 1.0f / (ea + eb);
            out[(size_t)2 * (lo + j) + 0] = ea * inv;
            out[(size_t)2 * (lo + j) + 1] = eb * inv;
        }
    }
}

// ---------------------------------------------------------------------------
extern "C" void kernel_launch(void* const* d_in, const int* in_sizes, int n_in,
                              void* d_out, int out_size, void* d_ws, size_t ws_size,
                              hipStream_t stream)
{
    const float* x  = (const float*)d_in[0];
    const int*   ei = (const int*)d_in[1];
    const int    N  = in_sizes[0];
    const int    E  = in_sizes[1] / 2;
    const int* src = ei;
    const int* dst = ei + E;

    const float* W1l = (const float*)d_in[2];
    const float* b1l = (const float*)d_in[3];
    const float* W1r = (const float*)d_in[4];
    const float* gam = (const float*)d_in[5];
    const float* bet = (const float*)d_in[6];
    const float* mu  = (const float*)d_in[7];
    const float* var = (const float*)d_in[8];
    const float* W2l = (const float*)d_in[9];
    const float* b2l = (const float*)d_in[10];
    const float* W2r = (const float*)d_in[11];
    const float* W3l = (const float*)d_in[12];
    const float* b3l = (const float*)d_in[13];
    const float* W3r = (const float*)d_in[14];
    const float* W4l = (const float*)d_in[15];
    const float* b4l = (const float*)d_in[16];
    const float* W4r = (const float*)d_in[17];
    const float* Wd1 = (const float*)d_in[18];
    const float* bd1 = (const float*)d_in[19];
    const float* Wd2 = (const float*)d_in[20];
    const float* bd2 = (const float*)d_in[21];

    char*  base = (char*)d_ws;
    size_t off  = 0;
    auto alloc = [&](size_t bytes) { size_t p = off; off += (bytes + 63) & ~(size_t)63; return p; };
    float* inv_cnt  = (float*)(base + alloc((size_t)N * 4));
    int*   binCnt   = (int*)  (base + alloc(MAXB * 4));
    int*   binStart = (int*)  (base + alloc((MAXB + 1) * 4));
    int*   binCur   = (int*)  (base + alloc(MAXB * 4));
    iv2*   stg      = (iv2*)  (base + alloc((size_t)E * 8));
    bf16*  hA       = (bf16*) (base + alloc((size_t)N * 16 * 2));
    bf16*  hB       = (bf16*) (base + alloc((size_t)N * 16 * 2));
    (void)ws_size;

    int nbins = (N + SPAN - 1) / SPAN;        // 250 for N=100000 (<= MAXB)
    int nbPairs = (E + PBE - 1) / PBE;

    // --- partition edges by dst bin ---
    hipMemsetAsync(binCnt, 0, MAXB * sizeof(int), stream);
    k_hist<<<1024, 256, 0, stream>>>(dst, binCnt, E);
    k_binscan<<<1, 256, 0, stream>>>(binCnt, binStart, binCur, nbins, E);
    k_pairs<<<nbPairs, 256, 0, stream>>>(src, dst, binCur, stg, E);

    // --- fused per-bin layers (LDS aggregation, no global atomics) ---
    k_lyr1<<<nbins, 1024, 0, stream>>>(stg, binStart, x, W1l, b1l, W1r,
                                       gam, bet, mu, var, inv_cnt, hA, N);
    k_lyr16<<<nbins, 1024, 0, stream>>>(stg, binStart, inv_cnt, hA, W2l, b2l, W2r, hB, N);
    k_lyr16<<<nbins, 1024, 0, stream>>>(stg, binStart, inv_cnt, hB, W3l, b3l, W3r, hA, N);
    k_lyrfin<<<nbins, 1024, 0, stream>>>(stg, binStart, inv_cnt, hA, W4l, b4l, W4r,
                                         Wd1, bd1, Wd2, bd2, (float*)d_out, N);
}

// Round 9
// 257.057 us; speedup vs baseline: 3.9472x; 3.9472x over previous
//
#include <hip/hip_runtime.h>
#include <hip/hip_bf16.h>

#define EPS  1e-5f
#define SPAN 400          // dst nodes per bin
#define MAXB 256          // max bins (N <= 102400)
#define PBE  2048         // edges per k_pairs block
typedef __hip_bfloat16 bf16;
typedef int iv4 __attribute__((ext_vector_type(4)));
typedef int iv2 __attribute__((ext_vector_type(2)));

// ---------------------------------------------------------------------------
// Pass 1: bin histogram of dst (bin = d/SPAN). Edge stream nt, read once.
// ---------------------------------------------------------------------------
__global__ void k_hist(const int* __restrict__ dst, int* __restrict__ binCnt, int nE)
{
    __shared__ int hist[MAXB];
    int t = threadIdx.x;
    for (int k = t; k < MAXB; k += blockDim.x) hist[k] = 0;
    __syncthreads();
    int tid = blockIdx.x * blockDim.x + t;
    int stride = gridDim.x * blockDim.x;
    const iv4* d4 = (const iv4*)dst;
    int n4 = nE >> 2;
    for (int e = tid; e < n4; e += stride) {
        iv4 d = __builtin_nontemporal_load(&d4[e]);
        atomicAdd(&hist[d.x / SPAN], 1);
        atomicAdd(&hist[d.y / SPAN], 1);
        atomicAdd(&hist[d.z / SPAN], 1);
        atomicAdd(&hist[d.w / SPAN], 1);
    }
    if (blockIdx.x == 0 && t == 0)
        for (int e = n4 << 2; e < nE; ++e) atomicAdd(&hist[dst[e] / SPAN], 1);
    __syncthreads();
    for (int k = t; k < MAXB; k += blockDim.x)
        if (hist[k]) atomicAdd(&binCnt[k], hist[k]);
}

// ---------------------------------------------------------------------------
// Exclusive scan of bin counts (one 256-thread block)
// ---------------------------------------------------------------------------
__global__ void k_binscan(const int* __restrict__ binCnt, int* __restrict__ binStart,
                          int* __restrict__ binCur, int nbins, int nE)
{
    __shared__ int ls[MAXB];
    int t = threadIdx.x;
    ls[t] = (t < nbins) ? binCnt[t] : 0;
    __syncthreads();
#pragma unroll
    for (int off = 1; off < MAXB; off <<= 1) {
        int u = (t >= off) ? ls[t - off] : 0;
        __syncthreads();
        ls[t] += u;
        __syncthreads();
    }
    int start = (t == 0) ? 0 : ls[t - 1];
    if (t < nbins) { binStart[t] = start; binCur[t] = start; }
    if (t == 0) binStart[nbins] = nE;
}

// ---------------------------------------------------------------------------
// Pass 2: partition (dst,src) pairs into bin-contiguous staging.
// ---------------------------------------------------------------------------
__global__ void k_pairs(const int* __restrict__ src, const int* __restrict__ dst,
                        int* __restrict__ binCur, iv2* __restrict__ stg, int nE)
{
    __shared__ int hist[MAXB], base[MAXB], cur[MAXB];
    int t = threadIdx.x;
    for (int k = t; k < MAXB; k += 256) { hist[k] = 0; cur[k] = 0; }
    __syncthreads();
    const iv4* d4 = (const iv4*)dst;
    const iv4* s4 = (const iv4*)src;
    int n4 = nE >> 2;
    int i0 = blockIdx.x * (PBE / 4) + 2 * t;
    bool v0 = i0 < n4, v1 = i0 + 1 < n4;
    iv4 d0 = {0,0,0,0}, s0 = {0,0,0,0}, d1 = {0,0,0,0}, s1 = {0,0,0,0};
    if (v0) { d0 = __builtin_nontemporal_load(&d4[i0]);     s0 = __builtin_nontemporal_load(&s4[i0]); }
    if (v1) { d1 = __builtin_nontemporal_load(&d4[i0 + 1]); s1 = __builtin_nontemporal_load(&s4[i0 + 1]); }
    if (v0) {
        atomicAdd(&hist[d0.x / SPAN], 1); atomicAdd(&hist[d0.y / SPAN], 1);
        atomicAdd(&hist[d0.z / SPAN], 1); atomicAdd(&hist[d0.w / SPAN], 1);
    }
    if (v1) {
        atomicAdd(&hist[d1.x / SPAN], 1); atomicAdd(&hist[d1.y / SPAN], 1);
        atomicAdd(&hist[d1.z / SPAN], 1); atomicAdd(&hist[d1.w / SPAN], 1);
    }
    bool tailblk = (blockIdx.x == gridDim.x - 1) && (t == 0);
    if (tailblk)
        for (int e = n4 << 2; e < nE; ++e) atomicAdd(&hist[dst[e] / SPAN], 1);
    __syncthreads();
    for (int k = t; k < MAXB; k += 256) {
        int tot = hist[k];
        base[k] = tot ? atomicAdd(&binCur[k], tot) : 0;
    }
    __syncthreads();
#define EMIT(dd, ss_) { int b = (dd) / SPAN; \
        int p = base[b] + atomicAdd(&cur[b], 1); \
        iv2 pr; pr.x = (dd); pr.y = (ss_); stg[p] = pr; }
    if (v0) { EMIT(d0.x, s0.x) EMIT(d0.y, s0.y) EMIT(d0.z, s0.z) EMIT(d0.w, s0.w) }
    if (v1) { EMIT(d1.x, s1.x) EMIT(d1.y, s1.y) EMIT(d1.z, s1.z) EMIT(d1.w, s1.w) }
    if (tailblk)
        for (int e = n4 << 2; e < nE; ++e) { EMIT(dst[e], src[e]) }
#undef EMIT
}

// ---------------------------------------------------------------------------
// Pass 3: per-bin LDS counting sort -> rp, inv_cnt, csr.
// csr writes land in a contiguous ~51KB window per block (L2-local, written once).
// ---------------------------------------------------------------------------
__global__ __launch_bounds__(1024) void k_sortbin(
    const iv2* __restrict__ stg, const int* __restrict__ binStart,
    int* __restrict__ rp, float* __restrict__ inv_cnt, int* __restrict__ csr,
    int n, int nbins)
{
    __shared__ int cnt[SPAN];
    __shared__ int cur[SPAN];
    __shared__ int ls[512];
    int t = threadIdx.x;
    int bin = blockIdx.x, lo = bin * SPAN;
    int nn = min(SPAN, n - lo);
    for (int k = t; k < SPAN; k += 1024) cnt[k] = 0;
    __syncthreads();
    int e0 = binStart[bin], e1 = binStart[bin + 1];
    for (int e = e0 + t; e < e1; e += 1024) {
        iv2 p = __builtin_nontemporal_load(&stg[e]);
        atomicAdd(&cnt[p.x - lo], 1);
    }
    __syncthreads();
    if (t < 512) ls[t] = (t < nn) ? cnt[t] : 0;
    __syncthreads();
#pragma unroll
    for (int off = 1; off < 512; off <<= 1) {
        int u = (t >= off && t < 512) ? ls[t - off] : 0;
        __syncthreads();
        if (t < 512) ls[t] += u;
        __syncthreads();
    }
    if (t < nn) {
        int c = cnt[t];
        int excl = ls[t] - c;                // exclusive within bin
        cur[t] = excl;
        rp[lo + t] = e0 + excl;
        inv_cnt[lo + t] = 1.0f / fmaxf((float)c, 1.0f);
    }
    if (bin == nbins - 1 && t == 0) rp[n] = e1;
    __syncthreads();
    for (int e = e0 + t; e < e1; e += 1024) {
        iv2 p = __builtin_nontemporal_load(&stg[e]);
        int pos = atomicAdd(&cur[p.x - lo], 1);
        csr[e0 + pos] = p.y;
    }
}

// ---------------------------------------------------------------------------
// Layer 1: 16 lanes per node; shfl-reduce; BN+ReLU fused; bf16 out.
// ---------------------------------------------------------------------------
__global__ void k_l1g(const int* __restrict__ rp, const int* __restrict__ csr,
                      const float* __restrict__ inv_cnt, const float* __restrict__ x,
                      const float* __restrict__ W1l, const float* __restrict__ b1l,
                      const float* __restrict__ W1r,
                      const float* __restrict__ gam, const float* __restrict__ bet,
                      const float* __restrict__ mu,  const float* __restrict__ var,
                      bf16* __restrict__ hout, int n)
{
    __shared__ float sWl[16], sb[16], sWr[16], ssc[16], sbi[16];
    int t = threadIdx.x;
    if (t < 16) {
        sWl[t] = W1l[t]; sb[t] = b1l[t]; sWr[t] = W1r[t];
        float sc = gam[t] * rsqrtf(var[t] + EPS);
        ssc[t] = sc;
        sbi[t] = bet[t] - mu[t] * sc;
    }
    __syncthreads();
    int grp = t >> 4, f = t & 15;
    int i = blockIdx.x * 16 + grp;
    if (i >= n) return;
    int r0 = rp[i], r1 = rp[i + 1];
    float s = 0.0f;
    for (int k = r0 + f; k < r1; k += 16) s += x[csr[k]];
#pragma unroll
    for (int m = 8; m >= 1; m >>= 1) s += __shfl_xor(s, m, 64);
    float mean = s * inv_cnt[i];
    float xv = x[i];
    float v = fmaf(mean, sWl[f], sb[f]);
    v = fmaf(xv, sWr[f], v);
    v = fmaxf(fmaf(v, ssc[f], sbi[f]), 0.0f);
    hout[(size_t)i * 16 + f] = __float2bfloat16(v);
}

// ---------------------------------------------------------------------------
// Layers 2,3: fused gather-mean (16 bf16 feats) + 16->16 transform + ReLU.
// ---------------------------------------------------------------------------
__global__ void k_sage16(const int* __restrict__ rp, const int* __restrict__ csr,
                         const float* __restrict__ inv_cnt, const bf16* __restrict__ h,
                         const float* __restrict__ Wl, const float* __restrict__ bl,
                         const float* __restrict__ Wr,
                         bf16* __restrict__ hout, int n)
{
    __shared__ float sWlT[256], sWrT[256], sb[16];
    __shared__ float sA[16][17], sX[16][17];
    int t = threadIdx.x;
    {
        int j = t & 15, ii = t >> 4;
        sWlT[ii * 16 + j] = Wl[j * 16 + ii];
        sWrT[ii * 16 + j] = Wr[j * 16 + ii];
    }
    if (t < 16) sb[t] = bl[t];
    int grp = t >> 4, f = t & 15;
    int i = blockIdx.x * 16 + grp;
    bool valid = i < n;
    float acc = 0.0f, ic = 0.0f, hs = 0.0f;
    if (valid) {
        int r0 = rp[i], r1 = rp[i + 1];
#pragma unroll 4
        for (int k = r0; k < r1; ++k) {
            int nb = csr[k];
            acc += __bfloat162float(h[(size_t)nb * 16 + f]);
        }
        ic = inv_cnt[i];
        hs = __bfloat162float(h[(size_t)i * 16 + f]);
    }
    sA[grp][f] = acc * ic;
    sX[grp][f] = hs;
    __syncthreads();
    if (valid) {
        float o = sb[f];
#pragma unroll
        for (int ii = 0; ii < 16; ++ii) {
            o = fmaf(sA[grp][ii], sWlT[ii * 16 + f], o);
            o = fmaf(sX[grp][ii], sWrT[ii * 16 + f], o);
        }
        hout[(size_t)i * 16 + f] = __float2bfloat16(fmaxf(o, 0.0f));
    }
}

// ---------------------------------------------------------------------------
// Layer 4 + decoder + softmax, fused with gather.
// ---------------------------------------------------------------------------
__global__ void k_fin(const int* __restrict__ rp, const int* __restrict__ csr,
                      const float* __restrict__ inv_cnt, const bf16* __restrict__ h,
                      const float* __restrict__ W4l, const float* __restrict__ b4l,
                      const float* __restrict__ W4r,
                      const float* __restrict__ Wd1, const float* __restrict__ bd1,
                      const float* __restrict__ Wd2, const float* __restrict__ bd2,
                      float* __restrict__ out, int n)
{
    __shared__ float sW4lT[512], sW4rT[512], sb4[32];
    __shared__ float sWd1T[1024], sbd1[32], sWd2[64], sbd2[2];
    __shared__ float sA[16][17], sX[16][17], sH4[16][33];
    int t = threadIdx.x;
    for (int k = t; k < 512; k += 256) {
        int j = k >> 4, ii = k & 15;
        sW4lT[ii * 32 + j] = W4l[k];
        sW4rT[ii * 32 + j] = W4r[k];
    }
    for (int k = t; k < 1024; k += 256) {
        int j = k >> 5, ii = k & 31;
        sWd1T[ii * 32 + j] = Wd1[k];
    }
    if (t < 32) { sb4[t] = b4l[t]; sbd1[t] = bd1[t]; }
    if (t < 64) sWd2[t] = Wd2[t];
    if (t < 2)  sbd2[t] = bd2[t];
    int grp = t >> 4, f = t & 15;
    int i = blockIdx.x * 16 + grp;
    bool valid = i < n;
    float acc = 0.0f, ic = 0.0f, hs = 0.0f;
    if (valid) {
        int r0 = rp[i], r1 = rp[i + 1];
#pragma unroll 4
        for (int k = r0; k < r1; ++k) {
            int nb = csr[k];
            acc += __bfloat162float(h[(size_t)nb * 16 + f]);
        }
        ic = inv_cnt[i];
        hs = __bfloat162float(h[(size_t)i * 16 + f]);
    }
    sA[grp][f] = acc * ic;
    sX[grp][f] = hs;
    __syncthreads();
    float h4a = sb4[f], h4b = sb4[f + 16];
#pragma unroll
    for (int ii = 0; ii < 16; ++ii) {
        float a  = sA[grp][ii];
        float xx = sX[grp][ii];
        h4a = fmaf(a,  sW4lT[ii * 32 + f],      h4a);
        h4b = fmaf(a,  sW4lT[ii * 32 + f + 16], h4b);
        h4a = fmaf(xx, sW4rT[ii * 32 + f],      h4a);
        h4b = fmaf(xx, sW4rT[ii * 32 + f + 16], h4b);
    }
    sH4[grp][f] = h4a;
    sH4[grp][f + 16] = h4b;
    __syncthreads();
    float za = sbd1[f], zb = sbd1[f + 16];
#pragma unroll
    for (int k = 0; k < 32; ++k) {
        float hv = sH4[grp][k];
        za = fmaf(hv, sWd1T[k * 32 + f],      za);
        zb = fmaf(hv, sWd1T[k * 32 + f + 16], zb);
    }
    za = fmaxf(za, 0.0f);
    zb = fmaxf(zb, 0.0f);
    float o0 = za * sWd2[f]      + zb * sWd2[f + 16];
    float o1 = za * sWd2[32 + f] + zb * sWd2[32 + f + 16];
#pragma unroll
    for (int m = 8; m >= 1; m >>= 1) {
        o0 += __shfl_xor(o0, m, 64);
        o1 += __shfl_xor(o1, m, 64);
    }
    if (valid && f == 0) {
        o0 += sbd2[0]; o1 += sbd2[1];
        float mx = fmaxf(o0, o1);
        float e0 = expf(o0 - mx), e1 = expf(o1 - mx);
        float inv = 1.0f / (e0 + e1);
        out[(size_t)2 * i + 0] = e0 * inv;
        out[(size_t)2 * i + 1] = e1 * inv;
    }
}

// ---------------------------------------------------------------------------
extern "C" void kernel_launch(void* const* d_in, const int* in_sizes, int n_in,
                              void* d_out, int out_size, void* d_ws, size_t ws_size,
                              hipStream_t stream)
{
    const float* x  = (const float*)d_in[0];
    const int*   ei = (const int*)d_in[1];
    const int    N  = in_sizes[0];
    const int    E  = in_sizes[1] / 2;
    const int* src = ei;
    const int* dst = ei + E;

    const float* W1l = (const float*)d_in[2];
    const float* b1l = (const float*)d_in[3];
    const float* W1r = (const float*)d_in[4];
    const float* gam = (const float*)d_in[5];
    const float* bet = (const float*)d_in[6];
    const float* mu  = (const float*)d_in[7];
    const float* var = (const float*)d_in[8];
    const float* W2l = (const float*)d_in[9];
    const float* b2l = (const float*)d_in[10];
    const float* W2r = (const float*)d_in[11];
    const float* W3l = (const float*)d_in[12];
    const float* b3l = (const float*)d_in[13];
    const float* W3r = (const float*)d_in[14];
    const float* W4l = (const float*)d_in[15];
    const float* b4l = (const float*)d_in[16];
    const float* W4r = (const float*)d_in[17];
    const float* Wd1 = (const float*)d_in[18];
    const float* bd1 = (const float*)d_in[19];
    const float* Wd2 = (const float*)d_in[20];
    const float* bd2 = (const float*)d_in[21];

    char*  base = (char*)d_ws;
    size_t off  = 0;
    auto alloc = [&](size_t bytes) { size_t p = off; off += (bytes + 63) & ~(size_t)63; return p; };
    float* inv_cnt  = (float*)(base + alloc((size_t)N * 4));
    int*   rp       = (int*)  (base + alloc((size_t)(N + 1) * 4));
    int*   binCnt   = (int*)  (base + alloc(MAXB * 4));
    int*   binStart = (int*)  (base + alloc((MAXB + 1) * 4));
    int*   binCur   = (int*)  (base + alloc(MAXB * 4));
    int*   csr      = (int*)  (base + alloc((size_t)E * 4));
    // stg aliases hA/hB region: stg dead after k_sortbin, hA first written in k_l1g
    size_t regionOff = alloc((size_t)E * 8 > (size_t)N * 64 ? (size_t)E * 8 : (size_t)N * 64);
    iv2*   stg = (iv2*) (base + regionOff);
    bf16*  hA  = (bf16*)(base + regionOff);
    bf16*  hB  = hA + (size_t)N * 16;
    (void)ws_size;

    int nbins   = (N + SPAN - 1) / SPAN;       // 250 for N=100000
    int nbPairs = (E + PBE - 1) / PBE;
    int nbN16   = (N + 15) / 16;

    // --- partition edges by dst bin, then per-bin counting sort -> CSR ---
    hipMemsetAsync(binCnt, 0, MAXB * sizeof(int), stream);
    k_hist<<<1024, 256, 0, stream>>>(dst, binCnt, E);
    k_binscan<<<1, 256, 0, stream>>>(binCnt, binStart, binCur, nbins, E);
    k_pairs<<<nbPairs, 256, 0, stream>>>(src, dst, binCur, stg, E);
    k_sortbin<<<nbins, 1024, 0, stream>>>(stg, binStart, rp, inv_cnt, csr, N, nbins);

    // --- gather-based layers (R4 structure) ---
    k_l1g<<<nbN16, 256, 0, stream>>>(rp, csr, inv_cnt, x, W1l, b1l, W1r,
                                     gam, bet, mu, var, hA, N);
    k_sage16<<<nbN16, 256, 0, stream>>>(rp, csr, inv_cnt, hA, W2l, b2l, W2r, hB, N);
    k_sage16<<<nbN16, 256, 0, stream>>>(rp, csr, inv_cnt, hB, W3l, b3l, W3r, hA, N);
    k_fin<<<nbN16, 256, 0, stream>>>(rp, csr, inv_cnt, hA, W4l, b4l, W4r,
                                     Wd1, bd1, Wd2, bd2, (float*)d_out, N);
}